// Round 8
// baseline (133.642 us; speedup 1.0000x reference)
//
#include <hip/hip_runtime.h>
#include <hip/hip_cooperative_groups.h>

namespace cg = cooperative_groups;

#define BB 4
#define CC 3
#define HH 512
#define WW 512
#define NS 81              // 9 x 9 shifts
#define IMG (HH * WW)
#define CHW (CC * IMG)
#define STRIP 8            // rows per strip
#define NSTRIPS (HH / STRIP)             // 64
#define NBLK (BB * NSTRIPS)              // 256 blocks = exactly 1 per CU
#define NROWS (CC * STRIP)               // 24 row-iterations per wave
#define ROWS_PER_BLK ((BB * CC * HH) / NBLK)   // 24 output rows per block

// R19: every in-kernel theory has nulled in both directions (R13-R18:
// occupancy x3, VMEM /6, inner-loop form, pipelining, reduce layout -> all
// ~96us). Remaining model: ~52us non-fill is dominated by per-dispatch /
// graph-node overhead + gaps, invisible to kernel-internal changes. This
// round collapses the whole pipeline into ONE cooperative dispatch:
//   sims (R18 body) -> grid.sync -> redundant-per-block deterministic
//   argmax (324 coalesced fixed-order fp64 sums) -> shift-copy (24 rows/blk).
// Decisive either way: overhead theory right -> ~72-82us; wrong -> the
// fused kernel is ~50us and FINALLY shows up in top-5 with real counters.
__device__ double g_part[NSTRIPS][BB * NS];   // [strip][b*81+sim], 166 KB

// constant-index component select (folds after full unroll)
#define C4(v, i) ((i) == 0 ? (v).x : (i) == 1 ? (v).y : (i) == 2 ? (v).z : (v).w)

__global__ __launch_bounds__(576, 8) void k_all(const float* __restrict__ xref,
                                                const float* __restrict__ x,
                                                float* __restrict__ out,
                                                float* __restrict__ outTail) {
    // ================= phase 1: sims (R18 body, proven exact) =================
    int bid   = blockIdx.x;          // 0..255
    int strip = bid & (NSTRIPS - 1);
    int b     = bid >> 6;
    int tid  = threadIdx.x;
    int lane = tid & 63;
    int sxi  = tid >> 6;             // wave index == sx index (9 waves)
    int j0   = lane << 3;            // 8 floats per lane
    int sx   = sxi - 4;
    int ip0  = strip * STRIP;

    const float* xbase = x    + (size_t)b * CHW;
    const float* rbase = xref + (size_t)b * CHW;

    float acc[9];
#pragma unroll
    for (int s = 0; s < 9; ++s) acc[s] = 0.f;

    // software-pipelined over t = c*8 + rr (24 iterations)
    float4 xa, xb, ra, rb, nxa, nxb, nra, nrb;
    bool okc;
    {   // preload t = 0 (c=0, rr=0)
        int ii = ip0 + sx;
        okc = (unsigned)ii < HH;
        const float* xr  = xbase + ip0 * WW + j0;
        const float* rr_ = rbase + (okc ? ii : ip0) * WW + j0;  // clamp: unused if !okc
        xa = *(const float4*)xr;   xb = *(const float4*)(xr + 4);
        ra = *(const float4*)rr_;  rb = *(const float4*)(rr_ + 4);
    }

#pragma unroll 2
    for (int t = 0; t < NROWS; ++t) {
        bool okn = false;
        if (t < NROWS - 1) {         // issue next-row loads BEFORE computing t
            int tn = t + 1;
            int c  = tn >> 3;
            int ip = ip0 + (tn & 7);
            int ii = ip + sx;
            okn = (unsigned)ii < HH;
            const float* xr  = xbase + (size_t)c * IMG + ip * WW + j0;
            const float* rr_ = rbase + (size_t)c * IMG + (okn ? ii : ip) * WW + j0;
            nxa = *(const float4*)xr;   nxb = *(const float4*)(xr + 4);
            nra = *(const float4*)rr_;  nrb = *(const float4*)(rr_ + 4);
        }

        if (okc) {                   // wave-uniform
            float p0 = __shfl_up(rb.x, 1, 64);
            float p1 = __shfl_up(rb.y, 1, 64);
            float p2 = __shfl_up(rb.z, 1, 64);
            float p3 = __shfl_up(rb.w, 1, 64);
            if (lane == 0) { p0 = p1 = p2 = p3 = 0.f; }   // cols < 0 -> mask
            float n0 = __shfl_down(ra.x, 1, 64);
            float n1 = __shfl_down(ra.y, 1, 64);
            float n2 = __shfl_down(ra.z, 1, 64);
            float n3 = __shfl_down(ra.w, 1, 64);
            if (lane == 63) { n0 = n1 = n2 = n3 = 0.f; }  // cols >= 512 -> mask

#define P4(i) ((i) == 0 ? p0 : (i) == 1 ? p1 : (i) == 2 ? p2 : p3)
#define N4(i) ((i) == 0 ? n0 : (i) == 1 ? n1 : (i) == 2 ? n2 : n3)
#pragma unroll
            for (int syi = 0; syi < 9; ++syi) {
#pragma unroll
                for (int k = 0; k < 8; ++k) {
                    int i = k + syi;         // window index 0..15 (constant)
                    float wv = (i < 4)  ? P4(i)
                             : (i < 8)  ? C4(ra, i - 4)
                             : (i < 12) ? C4(rb, i - 8)
                             :            N4(i - 12);
                    float xv = (k < 4) ? C4(xa, k) : C4(xb, k - 4);
                    acc[syi] += xv * wv;
                }
            }
#undef P4
#undef N4
        }

        xa = nxa; xb = nxb; ra = nra; rb = nrb; okc = okn;   // rotate
    }

#pragma unroll
    for (int s = 0; s < 9; ++s) {
        float v = acc[s];
        for (int off = 32; off; off >>= 1) v += __shfl_down(v, off, 64);
        if (lane == 0)
            g_part[strip][b * NS + sxi * 9 + s] = (double)v;
    }

    // ============== grid-wide sync (cooperative; device-scope) ==============
    cg::this_grid().sync();

    // ====== phase 2: redundant per-block argmax (deterministic, ~1us) ======
    // Thread t<324 sums g_part[k][t] over k in FIXED ascending order ->
    // bit-identical totals in every block. Consecutive t -> consecutive
    // addresses (coalesced).
    __shared__ double vals[BB * NS];
    __shared__ int    sBest[BB];
    if (tid < BB * NS) {
        double s = 0.0;
#pragma unroll 4
        for (int k = 0; k < NSTRIPS; ++k) s += g_part[k][tid];
        vals[tid] = s;
    }
    __syncthreads();
    if (tid < BB) {
        const double* v = vals + tid * NS;
        int best = 0;
        double bv = v[0];
        for (int i = 1; i < NS; ++i)
            if (v[i] > bv) { bv = v[i]; best = i; }   // strict >: first index wins
        sBest[tid] = best;
        if (bid == 0) {              // tail written once
            outTail[tid * 2]     = (float)(best / 9 - 4);
            outTail[tid * 2 + 1] = (float)(best % 9 - 4);
        }
    }
    __syncthreads();

    // ============ phase 3: shift-copy 24 global rows per block ============
    // Copy body identical to the R11-R18 proven k_apply, re-indexed.
    for (int idx = tid; idx < ROWS_PER_BLK * (WW / 4); idx += 576) {
        int rloc = idx >> 7;                 // 0..23
        int jf4  = idx & 127;                // float4 index within row
        int grow = bid * ROWS_PER_BLK + rloc;// 0..6143
        int bc   = grow >> 9;                // /512
        int row  = grow & 511;
        int bb   = bc / CC;
        int bi = sBest[bb];
        int psx = bi / 9 - 4;
        int psy = bi % 9 - 4;
        int is  = row - psx;
        int jc  = jf4 << 2;
        float4 v = make_float4(0.f, 0.f, 0.f, 0.f);
        if ((unsigned)is < HH) {
            const float* src = x + (size_t)bc * IMG + is * WW;
            int js0 = jc - psy;
            if (js0 >= 0 && js0 + 3 < WW) {
                v = *(const float4*)(src + js0);   // 4B-aligned dwordx4, exact
            } else {
                float* vv = (float*)&v;
#pragma unroll
                for (int k = 0; k < 4; ++k) {
                    int js = js0 + k;
                    if ((unsigned)js < WW) vv[k] = src[js];
                }
            }
        }
        *(float4*)(out + (size_t)bc * IMG + row * WW + jc) = v;
    }
}

extern "C" void kernel_launch(void* const* d_in, const int* in_sizes, int n_in,
                              void* d_out, int out_size, void* d_ws, size_t ws_size,
                              hipStream_t stream) {
    const float* xref = (const float*)d_in[0];
    const float* x    = (const float*)d_in[1];
    float* out     = (float*)d_out;
    float* outTail = out + (size_t)BB * CHW;
    (void)d_ws; (void)ws_size;          // workspace unused (poison fill is unconditional)

    void* args[] = { (void*)&xref, (void*)&x, (void*)&out, (void*)&outTail };
    hipLaunchCooperativeKernel((const void*)k_all, dim3(NBLK), dim3(576),
                               args, 0, stream);
}

// Round 9
// 101.135 us; speedup vs baseline: 1.3214x; 1.3214x over previous
//
#include <hip/hip_runtime.h>

#define BB 4
#define CC 3
#define HH 512
#define WW 512
#define NS 81              // 9 x 9 shifts
#define IMG (HH * WW)
#define CHW (CC * IMG)
#define STRIP 16           // rows per k_sims block (R13 winner)
#define NSTRIPS (HH / STRIP)             // 32
#define NBLK (BB * CC * NSTRIPS)         // 384 blocks (ALL sx per block)
#define SLOTS (CC * NSTRIPS)             // 96 partials per (b, sim)

// R20: exact R13 base (95.8us best) + ONE change: batch-4 row loads.
// Ledger: TLP x3 null (R17), VMEM/6 null (R15), halo/inner form null
// (R12/R14/R15), reduce layout null (R18), cooperative fusion -31us trap
// (R19). The never-exercised axis is per-wave miss parallelism: every
// version held <=1 row's loads (16 lines) in flight vs ~900-2000cyc
// post-fill miss latency; R18's pipeline was silently destroyed by its
// VGPR<=32 cap (launch_bounds(576,8) -- VGPR_Count=32 proves no prefetch
// registers existed). Here: issue 16 loads (4 rows) before computing them,
// launch_bounds(576,1) so ~90 VGPRs are allowed. FP order identical to R13.
__device__ double g_part[(size_t)BB * NS * SLOTS];   // 249 KB, fully rewritten each launch
__device__ int    g_best[BB];

// constant-index component select (folds after full unroll)
#define C4(v, i) ((i) == 0 ? (v).x : (i) == 1 ? (v).y : (i) == 2 ? (v).z : (v).w)

// sim(b,sx,sy) = sum over c,i,j (both (i,j) and (i+sx,j+sy) in bounds) of
//               x[b,c,i,j] * x_ref[b,c,i+sx,j+sy]
__global__ __launch_bounds__(576, 1) void k_sims(const float* __restrict__ xref,
                                                 const float* __restrict__ x) {
    int bid   = blockIdx.x;
    int strip = bid % NSTRIPS;
    int bc    = bid / NSTRIPS;
    int b     = bc / CC;
    const float* xp = x    + (size_t)bc * IMG;
    const float* rp = xref + (size_t)bc * IMG;
    int tid  = threadIdx.x;
    int lane = tid & 63;
    int sxi  = tid >> 6;                 // wave index == sx index (9 waves)
    int j0   = lane << 3;                // 8 floats per lane
    int sx   = sxi - 4;
    int ip0  = strip * STRIP;

    float acc[9];
#pragma unroll
    for (int s = 0; s < 9; ++s) acc[s] = 0.f;

#pragma unroll
    for (int rg = 0; rg < STRIP; rg += 4) {
        // ---- issue ALL 16 loads for 4 rows up front (4x miss parallelism) ----
        float4 xa4[4], xb4[4], ra4[4], rb4[4];
        bool ok[4];
#pragma unroll
        for (int u = 0; u < 4; ++u) {
            int ip = ip0 + rg + u;       // x row (always in bounds)
            int ii = ip + sx;            // ref row (wave-uniform test)
            ok[u] = (unsigned)ii < HH;
            const float* xrow = xp + ip * WW + j0;
            const float* rrow = rp + (ok[u] ? ii : ip) * WW + j0;  // clamp; unused if !ok
            xa4[u] = *(const float4*)(xrow);        // x   cols j0   .. j0+3
            xb4[u] = *(const float4*)(xrow + 4);    // x   cols j0+4 .. j0+7
            ra4[u] = *(const float4*)(rrow);        // ref cols j0   .. j0+3
            rb4[u] = *(const float4*)(rrow + 4);    // ref cols j0+4 .. j0+7
        }

        // ---- compute the 4 rows in order (FP sequence identical to R13) ----
#pragma unroll
        for (int u = 0; u < 4; ++u) {
            if (!ok[u]) continue;        // wave-uniform
            float4 xa = xa4[u], xb = xb4[u], ra = ra4[u], rb = rb4[u];

            // halo: prev4 = ref cols j0-4..j0-1 (lane-1's rb), next4 = j0+8..j0+11
            float p0 = __shfl_up(rb.x, 1, 64);
            float p1 = __shfl_up(rb.y, 1, 64);
            float p2 = __shfl_up(rb.z, 1, 64);
            float p3 = __shfl_up(rb.w, 1, 64);
            if (lane == 0) { p0 = p1 = p2 = p3 = 0.f; }   // cols < 0 -> mask
            float n0 = __shfl_down(ra.x, 1, 64);
            float n1 = __shfl_down(ra.y, 1, 64);
            float n2 = __shfl_down(ra.z, 1, 64);
            float n3 = __shfl_down(ra.w, 1, 64);
            if (lane == 63) { n0 = n1 = n2 = n3 = 0.f; }  // cols >= 512 -> mask

#define P4(i) ((i) == 0 ? p0 : (i) == 1 ? p1 : (i) == 2 ? p2 : p3)
#define N4(i) ((i) == 0 ? n0 : (i) == 1 ? n1 : (i) == 2 ? n2 : n3)
#pragma unroll
            for (int syi = 0; syi < 9; ++syi) {
#pragma unroll
                for (int k = 0; k < 8; ++k) {
                    int i = k + syi;     // window index 0..15 (constant)
                    float wv = (i < 4)  ? P4(i)
                             : (i < 8)  ? C4(ra, i - 4)
                             : (i < 12) ? C4(rb, i - 8)
                             :            N4(i - 12);
                    float xv = (k < 4) ? C4(xa, k) : C4(xb, k - 4);
                    acc[syi] += xv * wv;
                }
            }
#undef P4
#undef N4
        }
    }

    // Each wave owns 9 disjoint sims (its sx) -> no LDS combine, no atomics.
    // Wave shuffle-reduce (fp32, R13-identical), lane 0 stores fp64 partial.
    int cs = (bc % CC) * NSTRIPS + strip;            // partial slot 0..95
#pragma unroll
    for (int s = 0; s < 9; ++s) {
        float v = acc[s];
        for (int off = 32; off; off >>= 1) v += __shfl_down(v, off, 64);
        if (lane == 0)
            g_part[((size_t)b * NS + sxi * 9 + s) * SLOTS + cs] = (double)v;
    }
}

// Tiny reduce (exact R13): one block per batch; thread t sums its sim's 96
// consecutive fp64 partials in fixed order -> deterministic, then
// first-index argmax (matches jnp.argmax), writes g_best + shift tail.
__global__ __launch_bounds__(128) void k_reduce(float* __restrict__ outTail) {
    int b = blockIdx.x;
    int t = threadIdx.x;
    __shared__ double vals[NS];
    if (t < NS) {
        const double* p = g_part + ((size_t)b * NS + t) * SLOTS;
        double s = 0.0;
        for (int i = 0; i < SLOTS; ++i) s += p[i];
        vals[t] = s;
    }
    __syncthreads();
    if (t == 0) {
        int best = 0;
        double bv = vals[0];
        for (int i = 1; i < NS; ++i)
            if (vals[i] > bv) { bv = vals[i]; best = i; }   // strict >: first index wins
        g_best[b] = best;
        outTail[b * 2]     = (float)(best / 9 - 4);
        outTail[b * 2 + 1] = (float)(best % 9 - 4);
    }
}

// Pure shift-copy: reads precomputed g_best[b] (wave-uniform scalar load).
// Copy body unchanged from R11-R19 (proven exact).
__global__ __launch_bounds__(256) void k_apply(const float* __restrict__ x,
                                               float* __restrict__ out) {
    int blk = blockIdx.x;
    int bc  = blk >> 8;                 // 256 blocks per image (512 rows / 2)
    int tid = threadIdx.x;
    int b   = bc / CC;

    int bi = g_best[b];
    int sx = bi / 9 - 4;
    int sy = bi % 9 - 4;

    int row = ((blk & 255) << 1) + (tid >> 7);
    int j0  = (tid & 127) << 2;
    int is  = row - sx;
    float4 v = make_float4(0.f, 0.f, 0.f, 0.f);
    if ((unsigned)is < HH) {
        const float* src = x + (size_t)bc * IMG + is * WW;
        int js0 = j0 - sy;
        if (js0 >= 0 && js0 + 3 < WW) {
            v = *(const float4*)(src + js0);   // 4B-aligned dwordx4, exact (R2-R20)
        } else {
            float* vv = (float*)&v;
#pragma unroll
            for (int k = 0; k < 4; ++k) {
                int js = js0 + k;
                if ((unsigned)js < WW) vv[k] = src[js];
            }
        }
    }
    *(float4*)(out + (size_t)bc * IMG + row * WW + j0) = v;
}

extern "C" void kernel_launch(void* const* d_in, const int* in_sizes, int n_in,
                              void* d_out, int out_size, void* d_ws, size_t ws_size,
                              hipStream_t stream) {
    const float* xref = (const float*)d_in[0];
    const float* x    = (const float*)d_in[1];
    float* out = (float*)d_out;
    (void)d_ws; (void)ws_size;          // workspace unused (poison fill is unconditional)

    k_sims<<<NBLK, 576, 0, stream>>>(xref, x);
    k_reduce<<<BB, 128, 0, stream>>>(out + (size_t)BB * CHW);

    int applyBlocks = (BB * CC * HH) / 2;   // 3072
    k_apply<<<applyBlocks, 256, 0, stream>>>(x, out);
}

// Round 11
// 97.207 us; speedup vs baseline: 1.3748x; 1.0404x over previous
//
#include <hip/hip_runtime.h>

#define BB 4
#define CC 3
#define HH 512
#define WW 512
#define NS 81              // 9 x 9 shifts
#define IMG (HH * WW)
#define CHW (CC * IMG)
#define STRIP 16           // rows per k_sims block (best-measured config)
#define NSTRIPS (HH / STRIP)             // 32
#define NBLK (BB * CC * NSTRIPS)         // 384 blocks (ALL sx per block)
#define SLOTS (CC * NSTRIPS)             // 96 partials per (b, sim)

// R22: identical to R21 (verbatim R13 winner, 95.8 us) -- R21's bench was
// an infrastructure failure (container died twice), not a kernel failure.
// Final model: the unconditional 256MiB poison fill (~43.5us) precedes our
// nodes and its L3/fabric write drain poisons the following ~35-40us of
// memory access -- why every kernel-level axis nulled: TLP x3 (R17),
// VMEM/6 (R15), inner form x3 (R12/R14/R15), reduce layout (R18),
// MLP x4 (R20, -5us), fusion (R19, -31us trap). Minimal per-wave load
// count + shuffle halo is empirically the cheapest shape during the drain
// window. 3-node graph, no fences, no VGPR caps.
__device__ double g_part[(size_t)BB * NS * SLOTS];   // 249 KB, fully rewritten each launch
__device__ int    g_best[BB];

// constant-index component select (folds after full unroll)
#define C4(v, i) ((i) == 0 ? (v).x : (i) == 1 ? (v).y : (i) == 2 ? (v).z : (v).w)

// sim(b,sx,sy) = sum over c,i,j (both (i,j) and (i+sx,j+sy) in bounds) of
//               x[b,c,i,j] * x_ref[b,c,i+sx,j+sy]
__global__ __launch_bounds__(576) void k_sims(const float* __restrict__ xref,
                                              const float* __restrict__ x) {
    int bid   = blockIdx.x;
    int strip = bid % NSTRIPS;
    int bc    = bid / NSTRIPS;
    int b     = bc / CC;
    const float* xp = x    + (size_t)bc * IMG;
    const float* rp = xref + (size_t)bc * IMG;
    int tid  = threadIdx.x;
    int lane = tid & 63;
    int sxi  = tid >> 6;                 // wave index == sx index (9 waves)
    int j0   = lane << 3;                // 8 floats per lane
    int sx   = sxi - 4;
    int ip0  = strip * STRIP;

    float acc[9];
#pragma unroll
    for (int s = 0; s < 9; ++s) acc[s] = 0.f;

#pragma unroll
    for (int rr = 0; rr < STRIP; ++rr) {
        int ip = ip0 + rr;               // x row (always in bounds)
        int ii = ip + sx;                // ref row (wave-uniform test)
        if ((unsigned)ii >= HH) continue;

        const float* xrow = xp + ip * WW + j0;
        const float* rrow = rp + ii * WW + j0;
        float4 xa = *(const float4*)(xrow);        // x   cols j0   .. j0+3
        float4 xb = *(const float4*)(xrow + 4);    // x   cols j0+4 .. j0+7
        float4 ra = *(const float4*)(rrow);        // ref cols j0   .. j0+3
        float4 rb = *(const float4*)(rrow + 4);    // ref cols j0+4 .. j0+7

        // halo: prev4 = ref cols j0-4..j0-1 (lane-1's rb), next4 = j0+8..j0+11
        float p0 = __shfl_up(rb.x, 1, 64);
        float p1 = __shfl_up(rb.y, 1, 64);
        float p2 = __shfl_up(rb.z, 1, 64);
        float p3 = __shfl_up(rb.w, 1, 64);
        if (lane == 0) { p0 = p1 = p2 = p3 = 0.f; }   // cols < 0 -> mask
        float n0 = __shfl_down(ra.x, 1, 64);
        float n1 = __shfl_down(ra.y, 1, 64);
        float n2 = __shfl_down(ra.z, 1, 64);
        float n3 = __shfl_down(ra.w, 1, 64);
        if (lane == 63) { n0 = n1 = n2 = n3 = 0.f; }  // cols >= 512 -> mask

#define P4(i) ((i) == 0 ? p0 : (i) == 1 ? p1 : (i) == 2 ? p2 : p3)
#define N4(i) ((i) == 0 ? n0 : (i) == 1 ? n1 : (i) == 2 ? n2 : n3)
#pragma unroll
        for (int syi = 0; syi < 9; ++syi) {
#pragma unroll
            for (int k = 0; k < 8; ++k) {
                int i = k + syi;         // window index 0..15 (constant)
                float wv = (i < 4)  ? P4(i)
                         : (i < 8)  ? C4(ra, i - 4)
                         : (i < 12) ? C4(rb, i - 8)
                         :            N4(i - 12);
                float xv = (k < 4) ? C4(xa, k) : C4(xb, k - 4);
                acc[syi] += xv * wv;
            }
        }
#undef P4
#undef N4
    }

    // Each wave owns 9 disjoint sims (its sx) -> no LDS combine, no atomics.
    // Wave shuffle-reduce (fp32), lane 0 stores fp64 partial.
    int cs = (bc % CC) * NSTRIPS + strip;            // partial slot 0..95
#pragma unroll
    for (int s = 0; s < 9; ++s) {
        float v = acc[s];
        for (int off = 32; off; off >>= 1) v += __shfl_down(v, off, 64);
        if (lane == 0)
            g_part[((size_t)b * NS + sxi * 9 + s) * SLOTS + cs] = (double)v;
    }
}

// Tiny reduce: one block per batch; thread t sums its sim's 96 consecutive
// fp64 partials (fixed order -> deterministic), then first-index argmax
// (matches jnp.argmax), writes g_best + shift tail.
__global__ __launch_bounds__(128) void k_reduce(float* __restrict__ outTail) {
    int b = blockIdx.x;
    int t = threadIdx.x;
    __shared__ double vals[NS];
    if (t < NS) {
        const double* p = g_part + ((size_t)b * NS + t) * SLOTS;
        double s = 0.0;
        for (int i = 0; i < SLOTS; ++i) s += p[i];
        vals[t] = s;
    }
    __syncthreads();
    if (t == 0) {
        int best = 0;
        double bv = vals[0];
        for (int i = 1; i < NS; ++i)
            if (vals[i] > bv) { bv = vals[i]; best = i; }   // strict >: first index wins
        g_best[b] = best;
        outTail[b * 2]     = (float)(best / 9 - 4);
        outTail[b * 2 + 1] = (float)(best % 9 - 4);
    }
}

// Pure shift-copy: reads precomputed g_best[b] (wave-uniform scalar load).
// Copy body unchanged from R11-R21 (proven exact).
__global__ __launch_bounds__(256) void k_apply(const float* __restrict__ x,
                                               float* __restrict__ out) {
    int blk = blockIdx.x;
    int bc  = blk >> 8;                 // 256 blocks per image (512 rows / 2)
    int tid = threadIdx.x;
    int b   = bc / CC;

    int bi = g_best[b];
    int sx = bi / 9 - 4;
    int sy = bi % 9 - 4;

    int row = ((blk & 255) << 1) + (tid >> 7);
    int j0  = (tid & 127) << 2;
    int is  = row - sx;
    float4 v = make_float4(0.f, 0.f, 0.f, 0.f);
    if ((unsigned)is < HH) {
        const float* src = x + (size_t)bc * IMG + is * WW;
        int js0 = j0 - sy;
        if (js0 >= 0 && js0 + 3 < WW) {
            v = *(const float4*)(src + js0);   // 4B-aligned dwordx4, exact (R2-R22)
        } else {
            float* vv = (float*)&v;
#pragma unroll
            for (int k = 0; k < 4; ++k) {
                int js = js0 + k;
                if ((unsigned)js < WW) vv[k] = src[js];
            }
        }
    }
    *(float4*)(out + (size_t)bc * IMG + row * WW + j0) = v;
}

extern "C" void kernel_launch(void* const* d_in, const int* in_sizes, int n_in,
                              void* d_out, int out_size, void* d_ws, size_t ws_size,
                              hipStream_t stream) {
    const float* xref = (const float*)d_in[0];
    const float* x    = (const float*)d_in[1];
    float* out = (float*)d_out;
    (void)d_ws; (void)ws_size;          // workspace unused (poison fill is unconditional)

    k_sims<<<NBLK, 576, 0, stream>>>(xref, x);
    k_reduce<<<BB, 128, 0, stream>>>(out + (size_t)BB * CHW);

    int applyBlocks = (BB * CC * HH) / 2;   // 3072
    k_apply<<<applyBlocks, 256, 0, stream>>>(x, out);
}